// Round 8
// baseline (173.736 us; speedup 1.0000x reference)
//
#include <hip/hip_runtime.h>
#include <hip/hip_bf16.h>

typedef __attribute__((ext_vector_type(4))) float f32x4;
typedef __attribute__((ext_vector_type(8))) short bf16x8;

// ---------------- workspace layout ----------------
#define WS_UPRIME 0u                                   // 256 h * 65536 B = 16 MB (u[b][s] bf16, swizzled)
#define WS_KREP   (16u*1024u*1024u)                    // region reused: Wg + Pg
#define KREP_H    66816u
#define WS_WG     WS_KREP                              // Wg[r][k] 128x64 f32 = 32 KB
#define WS_PG     (WS_WG + 32768u)                     // Pg[k][j] 64x64 f32 = 16 KB
#define WS_YPP    (WS_KREP + 256u*KREP_H)              // y'' [hm][b][l] bf16, 32 MB
#define WS_PT     (WS_YPP + 33554432u)                 // Pt [n][k] bf16, 256 KB

__device__ __forceinline__ unsigned short f2bf(float f) {
  unsigned u = __float_as_uint(f);
  u += 0x7fffu + ((u >> 16) & 1u);          // round-to-nearest-even
  return (unsigned short)(u >> 16);
}
__device__ __forceinline__ float bf2f(unsigned short s) {
  return __uint_as_float(((unsigned)s) << 16);
}
__device__ __forceinline__ float bcast_lane(float v, int lane) {
  return __uint_as_float((unsigned)__builtin_amdgcn_readlane((int)__float_as_uint(v), lane));
}

// ---- swizzled [64+][68] matrix helpers: logical (r,k) at r*68 + 4*((k>>2)^((r>>3)&7)) + (k&3)
__device__ __forceinline__ float ldM(const float* M, int r, int k) {
  return M[r*68 + 4*(((k>>2) ^ ((r>>3)&7))) + (k&3)];
}
__device__ __forceinline__ void stM(float* M, int r, int k, float v) {
  M[r*68 + 4*(((k>>2) ^ ((r>>3)&7))) + (k&3)] = v;
}

// ---------------- Kernel A: shared construct (block 0) + uprime + pt ----------------
// LDS floats: Wt[128][68] | M0[64][68] | M1b[64][68] (aliases Araw) | bd[64]
#define KA_LDS 69888

// D = S*S (both swizzled [64][68]); wave 0 only (tid 0..63), 8x8 tile per thread.
__device__ __forceinline__ void mat_sq88(const float* __restrict__ S, float* __restrict__ D, int tid) {
  const int r0 = (tid >> 3) * 8;
  const int c0g = (tid & 7) * 2;           // logical col-groups c0g, c0g+1
  f32x4 acc0[8], acc1[8];
  #pragma unroll
  for (int ii = 0; ii < 8; ii++) { acc0[ii] = {0,0,0,0}; acc1[ii] = {0,0,0,0}; }
  for (int kb = 0; kb < 16; kb++) {
    f32x4 b0[4], b1[4];
    #pragma unroll
    for (int d = 0; d < 4; d++) {
      int row = 4*kb + d, s = (row>>3)&7;
      b0[d] = *(const f32x4*)(S + row*68 + 4*(c0g ^ s));
      b1[d] = *(const f32x4*)(S + row*68 + 4*((c0g+1) ^ s));
    }
    #pragma unroll
    for (int ii = 0; ii < 8; ii++) {
      int ar = r0 + ii;
      f32x4 a = *(const f32x4*)(S + ar*68 + 4*(kb ^ ((ar>>3)&7)));
      #pragma unroll
      for (int d = 0; d < 4; d++) { acc0[ii] += a[d]*b0[d]; acc1[ii] += a[d]*b1[d]; }
    }
  }
  #pragma unroll
  for (int ii = 0; ii < 8; ii++) {
    int row = r0 + ii, s = (row>>3)&7;
    *(f32x4*)(D + row*68 + 4*(c0g ^ s))     = acc0[ii];
    *(f32x4*)(D + row*68 + 4*((c0g+1) ^ s)) = acc1[ii];
  }
}

__global__ __launch_bounds__(512) void k_shared(
    const float* __restrict__ Ain, const float* __restrict__ Bv,
    const float* __restrict__ dt,  const float* __restrict__ in,
    const float* __restrict__ Pproj, char* __restrict__ ws)
{
  extern __shared__ char sm2[];
  const int bid = blockIdx.x;
  const int tid = threadIdx.x;

  if (bid >= 2049) {                 // ---- pt role ----
    int idx = (bid - 2049)*512 + tid;
    int k = idx >> 8, n = idx & 255;
    ((unsigned short*)(ws + WS_PT))[n*512 + k] = f2bf(Pproj[idx]);
    return;
  }
  if (bid >= 1) {                    // ---- uprime role ----
    const int ob = bid - 1;
    const int hg = ob & 15, ypair = (ob >> 4) & 7, b = ob >> 7;
    const int h4 = tid & 15, sc = tid >> 4;
    const int h  = hg*16 + h4;
    const int s0 = ypair*256 + sc*8;
    unsigned int w[4];
    #pragma unroll
    for (int i = 0; i < 4; i++) {
      float f0 = in[((size_t)b*2048 + s0 + 2*i    )*256 + h];
      float f1 = in[((size_t)b*2048 + s0 + 2*i + 1)*256 + h];
      w[i] = (unsigned)f2bf(f0) | ((unsigned)f2bf(f1) << 16);
    }
    unsigned off = ((unsigned)(b*4096 + s0*2)) ^ (((unsigned)(b & 7)) << 4);
    *(uint4*)(ws + WS_UPRIME + (size_t)h*65536u + off) = make_uint4(w[0],w[1],w[2],w[3]);
    return;
  }

  // ---- block 0: shared construct (dt uniform) ----
  float* Wt   = (float*)sm2;            // [128][68] swizzled (row = r of W[r]=A^r B)
  float* M0   = Wt  + 128*68;           // [64][68] swizzled
  float* M1b  = M0  + 64*68;            // [64][68] swizzled (aliases Araw)
  float* Araw = M1b;
  float* bd   = M1b + 64*68;            // [64]

  const int ln = tid & 63, w8 = tid >> 6;
  const float dth = dt[0];
  const float hdt = 0.5f * dth;

  for (int i = tid; i < 4096; i += 512) {
    int r = i >> 6, k = i & 63;
    stM(Araw, r, k, Ain[i]);
  }
  __syncthreads();

  // phase a: wave-local forward substitution (lane = row; wave w8 owns 8(9) rhs cols)
  {
    const int nc = (w8 == 7) ? 9 : 8;
    float c[9];
    #pragma unroll
    for (int jj = 0; jj < 9; jj++) {
      float v = 0.f;
      int col = w8*8 + jj;
      if (jj < nc) {
        if (col < 64) v = ((ln==col)?1.f:0.f) + hdt*ldM(Araw, ln, col);
        else          v = dth * Bv[ln];
      }
      c[jj] = v;
    }
    const float invd = 1.f/(1.f - hdt*ldM(Araw, ln, ln));
    for (int nb = 0; nb < 16; nb++) {
      f32x4 cf = *(const f32x4*)(Araw + ln*68 + 4*(nb ^ ((ln>>3)&7)));   // logical cols 4nb..4nb+3
      #pragma unroll
      for (int d = 0; d < 4; d++) {
        const int n = 4*nb + d;
        const float coef = (ln > n) ? hdt*cf[d] : 0.f;
        #pragma unroll
        for (int jj = 0; jj < 9; jj++) {
          if (jj < nc) {
            float xn = bcast_lane(c[jj]*invd, n);
            c[jj] += coef * xn;
          }
        }
      }
    }
    #pragma unroll
    for (int jj = 0; jj < 9; jj++) {
      if (jj < nc) {
        int col = w8*8 + jj;
        float xv = c[jj]*invd;
        if (col < 64) stM(M0, ln, col, xv);
        else          bd[ln] = xv;
      }
    }
  }
  __syncthreads();
  // M0 = A_d, bd = B_d ; Araw dead (M1b reusable)

  // sq1 (wave0) || Wt row 0,1 init (waves 1,2)
  if (tid < 64) {
    mat_sq88(M0, M1b, tid);                          // M^2
  } else if (tid < 128) {
    int i = tid - 64;                                // Wt[1][i] = (A_d B_d)[i]
    float acc = 0.f;
    for (int kb = 0; kb < 16; kb++) {
      f32x4 a = *(const f32x4*)(M0 + i*68 + 4*(kb ^ ((i>>3)&7)));
      f32x4 bv = *(const f32x4*)(bd + 4*kb);
      acc += a[0]*bv[0] + a[1]*bv[1] + a[2]*bv[2] + a[3]*bv[3];
    }
    Wt[68 + i] = acc;                                // s(1)=0: plain
  } else if (tid < 192) {
    int i = tid - 128;
    Wt[i] = bd[i];                                   // Wt[0] = B_d (s(0)=0: plain)
  }
  __syncthreads();

  float* Mc = M1b; float* Mn = M0;
  #pragma unroll 1
  for (int it = 1; it <= 6; it++) {
    const int cnt = 1 << it;
    if (tid < 64) {
      mat_sq88(Mc, Mn, tid);                         // -> M^{2^{it+1}}
    } else if (cnt >= 32) {
      // ext88 on waves 1-2: Wt[cnt+j][i] = sum_k Mc[i][k]*Wt[j][k]; 8i x 4j tiles
      int t = tid - 64;
      if (t < 2*cnt) {
        int nj = cnt >> 2;
        int ib = (t / nj) * 8;
        int jb = (t % nj) * 4;
        float acc[4][8];
        for (int jj = 0; jj < 4; jj++)
          for (int ii = 0; ii < 8; ii++)
            acc[jj][ii] = 0.f;
        for (int kb = 0; kb < 16; kb++) {
          f32x4 w4[4], a4[8];
          #pragma unroll
          for (int jj=0;jj<4;jj++) w4[jj] = *(const f32x4*)(Wt + (jb+jj)*68 + 4*(kb ^ (((jb+jj)>>3)&7)));
          #pragma unroll
          for (int ii=0;ii<8;ii++) a4[ii] = *(const f32x4*)(Mc + (ib+ii)*68 + 4*(kb ^ (((ib+ii)>>3)&7)));
          #pragma unroll
          for (int jj=0;jj<4;jj++)
            #pragma unroll
            for (int ii=0;ii<8;ii++)
              acc[jj][ii] += a4[ii][0]*w4[jj][0] + a4[ii][1]*w4[jj][1] + a4[ii][2]*w4[jj][2] + a4[ii][3]*w4[jj][3];
        }
        #pragma unroll
        for (int jj=0;jj<4;jj++) {
          int orow = cnt + jb + jj, s = (orow>>3)&7;
          f32x4 o0 = {acc[jj][0],acc[jj][1],acc[jj][2],acc[jj][3]};
          f32x4 o1 = {acc[jj][4],acc[jj][5],acc[jj][6],acc[jj][7]};
          *(f32x4*)(Wt + orow*68 + 4*(((ib>>2)  ) ^ s)) = o0;
          *(f32x4*)(Wt + orow*68 + 4*(((ib>>2)+1) ^ s)) = o1;
        }
      }
    } else if (tid >= 192) {
      // scalar extend (cnt <= 16) on waves 3-7
      for (int u = tid - 192; u < 64*cnt; u += 320) {
        int j = u >> 6, i = u & 63;
        float acc = 0.f;
        for (int kb = 0; kb < 16; kb++) {
          f32x4 a = *(const f32x4*)(Mc + i*68 + 4*(kb ^ ((i>>3)&7)));
          f32x4 w = *(const f32x4*)(Wt + j*68 + 4*(kb ^ ((j>>3)&7)));
          acc += a[0]*w[0] + a[1]*w[1] + a[2]*w[2] + a[3]*w[3];
        }
        stM(Wt, cnt + j, i, acc);
      }
    }
    __syncthreads();
    { float* t_ = Mc; Mc = Mn; Mn = t_; }
  }
  // Mc = P = A_d^128, Wt complete (128 rows)

  float* Wg = (float*)(ws + WS_WG);     // [r][k] plain
  float* Pg = (float*)(ws + WS_PG);     // [k][j] plain
  for (int i = tid; i < 2048; i += 512) {
    int r = i >> 4, g = i & 15;
    ((f32x4*)Wg)[i] = *(const f32x4*)(Wt + r*68 + 4*(g ^ ((r>>3)&7)));
  }
  for (int i = tid; i < 1024; i += 512) {
    int r = i >> 4, g = i & 15;
    ((f32x4*)Pg)[i] = *(const f32x4*)(Mc + r*68 + 4*(g ^ ((r>>3)&7)));
  }
}

// ---------------- Kernel B: fused per-h {dv chain + K build in LDS + Toeplitz conv} ----------------
#define KB_LDS 132352   // 64KB scratch->u-image + 66816B K-image

__global__ __launch_bounds__(256, 1) void k_fused(const float* __restrict__ C,
                                                  const float* __restrict__ Dm,
                                                  char* __restrict__ ws) {
  extern __shared__ char sm[];
  float* W_l = (float*)sm;              // [128][68], kb XOR-swizzled
  float* P_l = W_l + 128*68;            // [64][68]
  float* dvl = P_l + 64*68;             // [32][68]
  float* red = dvl + 32*68;             // [256]
  unsigned short* Kimg = (unsigned short*)(sm + 65536);   // [2m][8s][2088]
  const int h = blockIdx.x;
  const int tid = threadIdx.x;

  { // load W (swizzled) + P from global (L2-shared across blocks)
    const f32x4* Wg4 = (const f32x4*)(ws + WS_WG);
    const f32x4* Pg4 = (const f32x4*)(ws + WS_PG);
    for (int idx = tid; idx < 2048; idx += 256) {
      int r = idx >> 4, kb = idx & 15;
      *(f32x4*)(W_l + r*68 + 4*(kb ^ ((r>>3)&7))) = Wg4[idx];
    }
    for (int idx = tid; idx < 1024; idx += 256) {
      int k = idx >> 4, kb = idx & 15;
      *(f32x4*)(P_l + k*68 + 4*kb) = Pg4[idx];
    }
  }
  // zero K-image padding
  for (int i = tid; i < 640; i += 256) {
    int ms = i/40, o = i%40, s = ms & 7;
    int pos = (o < s) ? o : 2048 + o;
    Kimg[ms*2088 + pos] = 0;
  }
  if (tid < 128) { int m = tid>>6, j = tid&63; dvl[(m*16)*68 + j] = C[(h*2+m)*64 + j]; }
  __syncthreads();

  // dv chain: dv[m][q] = dv[m][q-1] * P
  {
    const int j2 = tid & 127, ks = tid >> 7, m = j2 >> 6, j = j2 & 63;
    for (int q = 1; q < 16; q++) {
      const float* dr = dvl + (m*16+q-1)*68 + ks*32;
      float pp = 0.f;
      #pragma unroll
      for (int kk = 0; kk < 32; kk++) pp += dr[kk] * P_l[(ks*32+kk)*68 + j];
      red[tid] = pp;
      __syncthreads();
      if (tid < 128) dvl[(m*16+q)*68 + j] = red[j2] + red[j2+128];
      __syncthreads();
    }
  }

  // phase e: K[m][128q+r] = dv[m][q].W[r] (+D at t=0) -> 8 shifted reversed copies; 4x4 tiles
  {
    const int m  = tid >> 7;
    const int tl = tid & 127;
    const int qt = tl >> 5;             // 0..3
    const int rt = tl & 31;             // 0..31
    const float Dadd = Dm[h*2 + m];
    float acc[4][4];
    for (int qi = 0; qi < 4; qi++)
      for (int ri = 0; ri < 4; ri++)
        acc[qi][ri] = 0.f;
    for (int kb = 0; kb < 16; kb++) {
      f32x4 av[4], wv[4];
      #pragma unroll
      for (int qi=0;qi<4;qi++) av[qi] = *(const f32x4*)(dvl + (m*16+qt*4+qi)*68 + 4*kb);
      #pragma unroll
      for (int ri=0;ri<4;ri++) { int r = rt*4+ri; wv[ri] = *(const f32x4*)(W_l + r*68 + 4*(kb ^ ((r>>3)&7))); }
      #pragma unroll
      for (int qi=0;qi<4;qi++)
        #pragma unroll
        for (int ri=0;ri<4;ri++)
          acc[qi][ri] += av[qi][0]*wv[ri][0] + av[qi][1]*wv[ri][1] + av[qi][2]*wv[ri][2] + av[qi][3]*wv[ri][3];
    }
    #pragma unroll
    for (int qi=0;qi<4;qi++)
      #pragma unroll
      for (int ri=0;ri<4;ri++) {
        int q = qt*4+qi, r = rt*4+ri, t = q*128+r;
        float v = acc[qi][ri] + ((t==0)?Dadd:0.f);
        unsigned short u16v = f2bf(v);
        #pragma unroll
        for (int s=0;s<8;s++)
          Kimg[(m*8+s)*2088 + (2047 - t + s)] = u16v;
      }
  }
  __syncthreads();

  // stage u-image (overwrites W_l/P_l/dvl scratch)
  {
    const uint4* s1 = (const uint4*)(ws + WS_UPRIME + (size_t)h*65536u);
    uint4* d1 = (uint4*)sm;
    for (int i = tid; i < 4096; i += 256) d1[i] = s1[i];
  }
  __syncthreads();

  // ---- conv: 16-tile Toeplitz ring (1 A-load + 1 B-load per 16 MFMAs) ----
  const int wid = tid >> 6, lane = tid & 63;
  const int m = wid & 1, par = wid >> 1;
  const int c = lane & 15, p = lane >> 4;

  const int ssel = (1 + (c & 7)) & 7;
  const int Xb = 2047 + 8*p - c + ssel;
  const char* Abase = sm + 65536 + m*33408 + ssel*4176 + 2*Xb;   // addr(d) = Abase - 2d
  const unsigned bkey = ((unsigned)(c & 7)) << 4;
  const int brow = c*4096 + 16*p;

  unsigned short* Y = (unsigned short*)(ws + WS_YPP);
  const size_t yoff = ((size_t)((h*2+m)*16 + c)) * 2048u;

#define BLD(S) (*(const bf16x8*)(sm + (((unsigned)(brow + 64*(S))) ^ bkey)))

#define MMX(t, u, BR, FIN) \
    if (!(FIN) || ((t) >= (u))) \
      acc[t] = __builtin_amdgcn_mfma_f32_16x16x32_bf16(fr[((t)-(u)) & 15], BR, acc[t], 0, 0, 0);

#define STEPX(u, BR, FIN) { \
    MMX(15, u, BR, FIN) \
    if (!(FIN)) { fr[(15-(u)) & 15] = *(const bf16x8*)(Ab2 + 64*(kt + (u) + 1)); } \
    MMX(14, u, BR, FIN) MMX(13, u, BR, FIN) MMX(12, u, BR, FIN) MMX(11, u, BR, FIN) \
    MMX(10, u, BR, FIN) MMX(9, u, BR, FIN) MMX(8, u, BR, FIN) MMX(7, u, BR, FIN) \
    MMX(6, u, BR, FIN) MMX(5, u, BR, FIN) MMX(4, u, BR, FIN) MMX(3, u, BR, FIN) \
    MMX(2, u, BR, FIN) MMX(1, u, BR, FIN) MMX(0, u, BR, FIN) }

#define CHUNK16(FIN) { \
    bn[0]=BLD(kt+1); bn[1]=BLD(kt+2); bn[2]=BLD(kt+3); bn[3]=BLD(kt+4); \
    bn[4]=BLD(kt+5); bn[5]=BLD(kt+6); bn[6]=BLD(kt+7); bn[7]=BLD(kt+8); \
    STEPX(0, bc, FIN) \
    bm[0]=BLD(kt+9);  bm[1]=BLD(kt+10); bm[2]=BLD(kt+11); bm[3]=BLD(kt+12); \
    bm[4]=BLD(kt+13); bm[5]=BLD(kt+14); bm[6]=BLD(kt+15); \
    if (!(FIN)) bm[7]=BLD(kt+16); \
    STEPX(1,  bn[0], FIN) STEPX(2,  bn[1], FIN) STEPX(3,  bn[2], FIN) STEPX(4,  bn[3], FIN) \
    STEPX(5,  bn[4], FIN) STEPX(6,  bn[5], FIN) STEPX(7,  bn[6], FIN) STEPX(8,  bn[7], FIN) \
    STEPX(9,  bm[0], FIN) STEPX(10, bm[1], FIN) STEPX(11, bm[2], FIN) STEPX(12, bm[3], FIN) \
    STEPX(13, bm[4], FIN) STEPX(14, bm[5], FIN) STEPX(15, bm[6], FIN) \
    if (!(FIN)) bc = bm[7]; \
  }

  #pragma unroll 1
  for (int gi = 0; gi < 4; gi++) {              // 16 owned L-tiles j = 32gi+par+2t
    const int dbase = 512*gi + 16*par;
    const char* Ab2 = Abase - 2*dbase;          // reload addr(step S) = Ab2 + 64*S ; init = Ab2 - 64*s
    const f32x4 zero4 = {0.f,0.f,0.f,0.f};
    f32x4 acc[16];
    bf16x8 fr[16], bn[8], bm[8], bc;
    #pragma unroll
    for (int t = 0; t < 16; t++) acc[t] = zero4;
    #pragma unroll
    for (int s = 0; s < 16; s++) fr[s] = *(const bf16x8*)(Ab2 - 64*s);   // d = dbase + 32s
    bc = BLD(0);

    int kt = 0;
    #pragma unroll 1
    for (int cc = 0; cc < gi; cc++) { CHUNK16(0) kt += 16; }
    CHUNK16(1)

    #pragma unroll
    for (int t = 0; t < 16; t++) {              // y''[hm][b][l] bf16
      int l0 = 16*(32*gi + par + 2*t) + 4*p;
      unsigned w0 = (unsigned)f2bf(acc[t][0]) | ((unsigned)f2bf(acc[t][1]) << 16);
      unsigned w1 = (unsigned)f2bf(acc[t][2]) | ((unsigned)f2bf(acc[t][3]) << 16);
      *(uint2*)(Y + yoff + (unsigned)l0) = make_uint2(w0, w1);
    }
  }
#undef CHUNK16
#undef STEPX
#undef MMX
#undef BLD
}

// ---------------- K5: gelu + transpose-stage + projection GEMM ----------------
__global__ __launch_bounds__(256) void k_proj(const char* __restrict__ ws, float* __restrict__ out) {
  __shared__ __align__(16) unsigned short At[128*64];
  __shared__ __align__(16) unsigned short Bt[256*64];
  const int tid = threadIdx.x;
  const int wid = tid >> 6, lane = tid & 63;
  const int c = lane & 15, p = lane >> 4;
  const int R0 = blockIdx.x * 128;
  const unsigned short* Ypp = (const unsigned short*)(ws + WS_YPP);
  const unsigned short* Pt  = (const unsigned short*)(ws + WS_PT);

  const f32x4 zero4 = {0.f,0.f,0.f,0.f};
  f32x4 acc[2][16];
  #pragma unroll
  for (int mt = 0; mt < 2; mt++)
    #pragma unroll
    for (int nt = 0; nt < 16; nt++) acc[mt][nt] = zero4;

  for (int ks = 0; ks < 8; ks++) {
    const int Kt = ks * 64;
    __syncthreads();
    #pragma unroll
    for (int i = 0; i < 4; i++) {
      int unit = tid + 256*i;
      int ku = unit >> 4;
      int ro = unit & 15;
      uint4 v = *(const uint4*)(Ypp + (size_t)(Kt + ku)*32768u + R0 + ro*8);
      const unsigned short* vs = (const unsigned short*)&v;
      #pragma unroll
      for (int e = 0; e < 8; e++) {
        float y = bf2f(vs[e]);
        float gl = 0.5f * y * (1.0f + erff(y * 0.70710678118654752f));
        int row = ro*8 + e;
        At[row*64 + ((((unsigned)(ku*2)) ^ (((unsigned)(row & 7)) << 4)) >> 1)] = f2bf(gl);
      }
    }
    #pragma unroll
    for (int i = 0; i < 8; i++) {
      int unit = tid + 256*i;
      int n = unit >> 3;
      int ko = unit & 7;
      uint4 v = *(const uint4*)(Pt + (size_t)n*512u + Kt + ko*8);
      *(uint4*)((char*)Bt + n*128 + (((unsigned)(ko*16)) ^ (((unsigned)(n & 7)) << 4))) = v;
    }
    __syncthreads();

    bf16x8 a[2][2];
    #pragma unroll
    for (int mt = 0; mt < 2; mt++) {
      int row = wid*32 + mt*16 + c;
      a[mt][0] = *(const bf16x8*)((char*)At + row*128 + (((unsigned)(16*p     )) ^ (((unsigned)(row & 7)) << 4)));
      a[mt][1] = *(const bf16x8*)((char*)At + row*128 + (((unsigned)(16*p + 64)) ^ (((unsigned)(row & 7)) << 4)));
    }
    #pragma unroll
    for (int nt = 0; nt < 16; nt++) {
      int n = nt*16 + c;
      bf16x8 b0 = *(const bf16x8*)((char*)Bt + n*128 + (((unsigned)(16*p     )) ^ (((unsigned)(n & 7)) << 4)));
      bf16x8 b1 = *(const bf16x8*)((char*)Bt + n*128 + (((unsigned)(16*p + 64)) ^ (((unsigned)(n & 7)) << 4)));
      #pragma unroll
      for (int mt = 0; mt < 2; mt++) {
        acc[mt][nt] = __builtin_amdgcn_mfma_f32_16x16x32_bf16(a[mt][0], b0, acc[mt][nt], 0,0,0);
        acc[mt][nt] = __builtin_amdgcn_mfma_f32_16x16x32_bf16(a[mt][1], b1, acc[mt][nt], 0,0,0);
      }
    }
  }
  #pragma unroll
  for (int mt = 0; mt < 2; mt++)
    #pragma unroll
    for (int nt = 0; nt < 16; nt++)
      #pragma unroll
      for (int r = 0; r < 4; r++) {
        int row = R0 + wid*32 + mt*16 + 4*p + r;
        out[(size_t)row*256 + nt*16 + c] = acc[mt][nt][r];
      }
}

// ---------------- host ----------------
extern "C" void kernel_launch(void* const* d_in, const int* in_sizes, int n_in,
                              void* d_out, int out_size, void* d_ws, size_t ws_size,
                              hipStream_t stream) {
  (void)in_sizes; (void)n_in; (void)out_size; (void)ws_size;
  const float* in  = (const float*)d_in[0];
  const float* A   = (const float*)d_in[1];
  const float* Bv  = (const float*)d_in[2];
  const float* dt  = (const float*)d_in[3];
  const float* C   = (const float*)d_in[4];
  const float* Dm  = (const float*)d_in[5];
  const float* P   = (const float*)d_in[6];
  char* ws = (char*)d_ws;
  float* out = (float*)d_out;

  hipFuncSetAttribute(reinterpret_cast<const void*>(k_shared),
                      hipFuncAttributeMaxDynamicSharedMemorySize, KA_LDS);
  hipFuncSetAttribute(reinterpret_cast<const void*>(k_fused),
                      hipFuncAttributeMaxDynamicSharedMemorySize, KB_LDS);

  hipLaunchKernelGGL(k_shared, dim3(2305), dim3(512), KA_LDS, stream, A, Bv, dt, in, P, ws);
  hipLaunchKernelGGL(k_fused,  dim3(256),  dim3(256), KB_LDS, stream, C, Dm, ws);
  hipLaunchKernelGGL(k_proj,   dim3(256),  dim3(256), 0,      stream, ws, out);
}